// Round 1
// baseline (1674.609 us; speedup 1.0000x reference)
//
#include <hip/hip_runtime.h>

// OnlineLSTM: B=8192, T=2048, I=1, H=50. One block = 16 batch rows, 4 waves.
// Wave w owns hidden-columns j = 16w .. 16w+15 for ALL four gates (gate-major
// padded N=256 => tiles co-locate i,f,g,o of a (b,j) in the same lane).
// K padded 50->64; k=50 carries x_t (W_ih row), k=51 carries 1.0 (bias row),
// so the MFMA output IS the full pre-activation z. h round-trips through a
// double-buffered fp16 LDS tile; c stays fp32 in registers.

#define HID   50
#define NSTEP 2048
#define BPB   16    // batch per block
#define HSTR  72    // fp16 elems per hbuf row: 144 B, 16B-aligned, bank-spread

typedef _Float16 half8  __attribute__((ext_vector_type(8)));
typedef float    float4v __attribute__((ext_vector_type(4)));

__device__ __forceinline__ float fast_sig(float z) {
    // 1/(1+exp(-z));  exp overflow -> rcp(inf)=0 -> correct saturation
    float e = __builtin_amdgcn_exp2f(-1.4426950408889634f * z);
    return __builtin_amdgcn_rcpf(1.0f + e);
}
__device__ __forceinline__ float fast_tanh(float z) {
    // 1 - 2/(1+exp(2z)); saturates correctly at +/-1
    float e = __builtin_amdgcn_exp2f(2.8853900817779268f * z);
    return 1.0f - 2.0f * __builtin_amdgcn_rcpf(1.0f + e);
}

__global__ __launch_bounds__(256) void lstm_fused(
    const float* __restrict__ x,
    const float* __restrict__ W_ih,
    const float* __restrict__ W_hh,
    const float* __restrict__ b_ih,
    const float* __restrict__ b_hh,
    const float* __restrict__ W_lin,
    const float* __restrict__ b_lin,
    float* __restrict__ out)
{
    __shared__ __align__(16) _Float16 hbuf[2][BPB][HSTR];

    const int tid  = threadIdx.x;
    const int wave = tid >> 6;
    const int lane = tid & 63;
    const int col  = lane & 15;   // MFMA n-col (and A m-row for loads)
    const int quad = lane >> 4;   // MFMA k-group / C-row group
    const int b0   = blockIdx.x * BPB;
    const int j    = wave * 16 + col;  // hidden column this lane owns

    // ---- init h buffers: zeros, then x_0 at col 50 and 1.0 at col 51 ----
    for (int i = tid; i < 2 * BPB * HSTR; i += 256)
        (&hbuf[0][0][0])[i] = (_Float16)0.0f;
    __syncthreads();
    if (tid < BPB) {
        hbuf[0][tid][HID]     = (_Float16)x[(size_t)(b0 + tid) * NSTEP];
        hbuf[0][tid][HID + 1] = (_Float16)1.0f;
        hbuf[1][tid][HID + 1] = (_Float16)1.0f;
    }

    // ---- persistent B fragments: Wt[k][n], n_local = lane&15, k = kt*32+quad*8+jj
    // tile (gate g, jt=wave): column = row g*50 + j of [W_hh | W_ih | b] ----
    half8 bfrag[4][2];
    for (int g = 0; g < 4; ++g)
        for (int kt = 0; kt < 2; ++kt) {
            half8 f;
            #pragma unroll
            for (int jj = 0; jj < 8; ++jj) {
                int k = kt * 32 + quad * 8 + jj;
                float v = 0.0f;
                if (j < HID) {
                    int row = g * HID + j;
                    if (k < HID)           v = W_hh[row * HID + k];
                    else if (k == HID)     v = W_ih[row];
                    else if (k == HID + 1) v = b_ih[row] + b_hh[row];
                }
                f[jj] = (_Float16)v;
            }
            bfrag[g][kt] = f;
        }

    float c[4] = {0.f, 0.f, 0.f, 0.f};
    const bool xloader = (wave == 3) && (quad == 0);  // wave 3 has least real EW work
    const float* xrow = x + (size_t)(b0 + col) * NSTEP;

    __syncthreads();

    for (int t = 0; t < NSTEP; ++t) {
        const int cur = t & 1;
        const int nxt = cur ^ 1;

        // prefetch next timestep's x (L1-resident: 16 lines/block reused 16x)
        float xn = 0.f;
        if (xloader) {
            int tt = (t + 1 < NSTEP) ? (t + 1) : (NSTEP - 1);
            xn = xrow[tt];
        }

        // A fragments: A[m=col][k=quad*8+jj (+32)] from fp16 h buffer
        const _Float16* arow = &hbuf[cur][col][0];
        half8 a0 = *(const half8*)(arow + quad * 8);
        half8 a1 = *(const half8*)(arow + 32 + quad * 8);

        float4v d0 = {0.f, 0.f, 0.f, 0.f}, d1 = d0, d2 = d0, d3 = d0;
        d0 = __builtin_amdgcn_mfma_f32_16x16x32_f16(a0, bfrag[0][0], d0, 0, 0, 0);
        d1 = __builtin_amdgcn_mfma_f32_16x16x32_f16(a0, bfrag[1][0], d1, 0, 0, 0);
        d2 = __builtin_amdgcn_mfma_f32_16x16x32_f16(a0, bfrag[2][0], d2, 0, 0, 0);
        d3 = __builtin_amdgcn_mfma_f32_16x16x32_f16(a0, bfrag[3][0], d3, 0, 0, 0);
        d0 = __builtin_amdgcn_mfma_f32_16x16x32_f16(a1, bfrag[0][1], d0, 0, 0, 0);
        d1 = __builtin_amdgcn_mfma_f32_16x16x32_f16(a1, bfrag[1][1], d1, 0, 0, 0);
        d2 = __builtin_amdgcn_mfma_f32_16x16x32_f16(a1, bfrag[2][1], d2, 0, 0, 0);
        d3 = __builtin_amdgcn_mfma_f32_16x16x32_f16(a1, bfrag[3][1], d3, 0, 0, 0);

        // gate math: z is complete (bias+input folded into K). C-layout:
        // col = lane&15, row = quad*4 + r  -> batch row b = quad*4 + r
        _Float16 hv[4];
        #pragma unroll
        for (int r = 0; r < 4; ++r) {
            float ig = fast_sig(d0[r]);
            float fg = fast_sig(d1[r]);
            float gg = fast_tanh(d2[r]);
            float og = fast_sig(d3[r]);
            float cn = fg * c[r] + ig * gg;
            c[r] = cn;
            hv[r] = (_Float16)(og * fast_tanh(cn));
        }
        if (j < HID) {
            #pragma unroll
            for (int r = 0; r < 4; ++r)
                hbuf[nxt][quad * 4 + r][j] = hv[r];
        }
        if (xloader)
            hbuf[nxt][col][HID] = (_Float16)xn;

        __syncthreads();
    }

    // ---- epilogue: out[b] = h_last . W_lin + b_lin ; final h is in hbuf[0] ----
    if (tid < BPB) {
        float s = b_lin[0];
        for (int k = 0; k < HID; ++k)
            s += (float)hbuf[0][tid][k] * W_lin[k];
        out[b0 + tid] = s;
    }
}

extern "C" void kernel_launch(void* const* d_in, const int* in_sizes, int n_in,
                              void* d_out, int out_size, void* d_ws, size_t ws_size,
                              hipStream_t stream) {
    const float* x     = (const float*)d_in[0];
    const float* W_ih  = (const float*)d_in[1];
    const float* W_hh  = (const float*)d_in[2];
    const float* b_ih  = (const float*)d_in[3];
    const float* b_hh  = (const float*)d_in[4];
    const float* W_lin = (const float*)d_in[5];
    const float* b_lin = (const float*)d_in[6];
    float* outp = (float*)d_out;
    dim3 grid(8192 / BPB), block(256);
    hipLaunchKernelGGL(lstm_fused, grid, block, 0, stream,
                       x, W_ih, W_hh, b_ih, b_hh, W_lin, b_lin, outp);
}